// Round 9
// baseline (2447.493 us; speedup 1.0000x reference)
//
#include <hip/hip_runtime.h>

typedef unsigned short ushort_t;
typedef unsigned int u32;
typedef __attribute__((ext_vector_type(8))) short bf16x8;
typedef __attribute__((ext_vector_type(4))) float f32x4;
typedef __attribute__((ext_vector_type(2))) float f32x2;
typedef __attribute__((ext_vector_type(4))) u32 u32x4;

#define NTOT 262144  // B*D columns

__device__ __forceinline__ ushort_t f2b_rne(float f) {
    u32 u = __builtin_bit_cast(u32, f);
    u32 r = u + 0x7FFFu + ((u >> 16) & 1u);
    return (ushort_t)(r >> 16);
}
// (even,odd) f32 pair * (s,s) -> packed bf16 dword (RNE): v_pk_mul_f32 + v_cvt_pk_bf16_f32
__device__ __forceinline__ u32 scale_pack(f32x2 xp, f32x2 s) {
    f32x2 d;
    asm("v_pk_mul_f32 %0, %1, %2" : "=v"(d) : "v"(xp), "v"(s));
    u32 r;
    asm("v_cvt_pk_bf16_f32 %0, %1, %2" : "=v"(r) : "v"(d[0]), "v"(d[1]));
    return r;
}

// ---- prep: x (B,64,32) f32 -> x0bf bf16 [n=(b*32+d)][64 h] (RNE) ----
__global__ void cin_prep_x0bf(const float* __restrict__ x, ushort_t* __restrict__ x0bf) {
    __shared__ float xs[64 * 33];
    const int b = blockIdx.x, t = threadIdx.x;
    const float4* src = (const float4*)(x + (size_t)b * 2048);
#pragma unroll
    for (int i = 0; i < 2; ++i) {
        float4 f = src[t + 256 * i];
        int e = (t + 256 * i) * 4;
        int h = e >> 5, d = e & 31;
        xs[h * 33 + d]     = f.x;
        xs[h * 33 + d + 1] = f.y;
        xs[h * 33 + d + 2] = f.z;
        xs[h * 33 + d + 3] = f.w;
    }
    __syncthreads();
    const int d = t >> 3, j8 = t & 7;
    u32 w[4];
#pragma unroll
    for (int q = 0; q < 4; ++q) {
        int h0 = j8 * 8 + 2 * q;
        w[q] = (u32)f2b_rne(xs[h0 * 33 + d]) | ((u32)f2b_rne(xs[(h0 + 1) * 33 + d]) << 16);
    }
    uint4 o; o.x = w[0]; o.y = w[1]; o.z = w[2]; o.w = w[3];
    *(uint4*)(x0bf + ((size_t)b * 32 + d) * 64 + j8 * 8) = o;
}

// ---- prep: K (128,G,64) f32 -> Kp bf16 [g][k][64] (linear, no swizzle) ----
__global__ void cin_prep_k3(const float* __restrict__ K, ushort_t* __restrict__ Kp, int G) {
    const int g = blockIdx.x, t = threadIdx.x;
    const int k = t >> 1, j0 = (t & 1) * 32;  // ushort col base (each thread owns 32)
    const float* s = K + ((size_t)k * G + g) * 64 + j0;
    ushort_t* dst = Kp + (size_t)g * 8192 + k * 64 + j0;
#pragma unroll
    for (int c = 0; c < 4; ++c) {  // 4 chunks x 8 ushorts = 32  (R8 bug: was c<2)
        u32 w[4];
#pragma unroll
        for (int q = 0; q < 4; ++q) {
            int e = c * 8 + 2 * q;
            w[q] = (u32)f2b_rne(s[e]) | ((u32)f2b_rne(s[e + 1]) << 16);
        }
        uint4 o; o.x = w[0]; o.y = w[1]; o.z = w[2]; o.w = w[3];
        *(uint4*)(dst + c * 8) = o;
    }
}

// ---- layer: fm[n,k] = relu( sum_g sum_h K[k,g,h]*xi[n,g]*x0[n,h] + bias[k] )
// NO LDS, NO barriers in the main loop: A-fragments of K loaded directly from
// global (L2-resident, coalesced 16 rows x 64B per instr); B built in-register
// from resident x0 f32 pairs; xi in register chunks. One light __syncthreads
// per 8-g chunk keeps in-block waves phase-close for L1 reuse of K.
template <int G, bool STORE_FM>
__launch_bounds__(256, 2)
__global__ void cin_layer7(const ushort_t* __restrict__ x0bf,   // [NTOT][64]
                           const ushort_t* __restrict__ xi_src, // [NTOT][G] rows
                           const ushort_t* __restrict__ Kp,     // [G][128][64] linear
                           const float* __restrict__ bias,      // [128]
                           ushort_t* __restrict__ fm_out,       // [NTOT][128]
                           float* __restrict__ out,             // [B][384]
                           int layer_off) {
    constexpr int NC = G / 8;  // 8-g xi chunks

    const int t = threadIdx.x;
    const int wg = blockIdx.x;
    const int lane = t & 63;
    const int wave = t >> 6;
    const int wm = wave >> 1, wn = wave & 1;
    const int col = lane & 15, g4 = lane >> 4;
    const size_t n0 = (size_t)wg * 128;

    // per-thread xi row pointers (one per nf)
    const ushort_t* xrow[4];
#pragma unroll
    for (int nf = 0; nf < 4; ++nf)
        xrow[nf] = xi_src + (n0 + wn * 64 + nf * 16 + col) * G;

    // per-thread K fragment base: row (wm*64 + col), byte-chunk g4
    const ushort_t* kbase = Kp + (size_t)(wm * 64 + col) * 64 + g4 * 8;

    // ---- x0 base -> unpacked (even,odd) f32 pairs: 64 VGPRs ----
    f32x2 xb[4][8];
#pragma unroll
    for (int nf = 0; nf < 4; ++nf) {
        const size_t n_g = n0 + wn * 64 + nf * 16 + col;
#pragma unroll
        for (int ks2 = 0; ks2 < 2; ++ks2) {
            u32x4 v = *(const u32x4*)(x0bf + n_g * 64 + ks2 * 32 + g4 * 8);
#pragma unroll
            for (int q = 0; q < 4; ++q) {
                f32x2 p;
                p[0] = __builtin_bit_cast(float, v[q] << 16);
                p[1] = __builtin_bit_cast(float, v[q] & 0xFFFF0000u);
                xb[nf][ks2 * 4 + q] = p;
            }
        }
    }

    u32x4 xcA[4], xcB[4];
#pragma unroll
    for (int nf = 0; nf < 4; ++nf) xcA[nf] = *(const u32x4*)(xrow[nf]);  // chunk 0

    f32x4 acc[4][4];
#pragma unroll
    for (int a = 0; a < 4; ++a)
#pragma unroll
        for (int b = 0; b < 4; ++b) acc[a][b] = (f32x4){0.f, 0.f, 0.f, 0.f};

    // one g: 8 direct global loads of A-frags, register B-build, 32 MFMA
    auto PROC_G = [&](int g, const u32x4 (&cur)[4], int j, int sub) {
        const ushort_t* kg = kbase + (size_t)g * 8192;
        bf16x8 af[2][4];
#pragma unroll
        for (int ks2 = 0; ks2 < 2; ++ks2)
#pragma unroll
            for (int mf = 0; mf < 4; ++mf)
                af[ks2][mf] = *(const bf16x8*)(kg + mf * 1024 + ks2 * 32);
        bf16x8 bw[2][4];
#pragma unroll
        for (int nf = 0; nf < 4; ++nf) {
            u32 xw = cur[nf][j];
            u32 xs32 = sub ? (xw & 0xFFFF0000u) : (xw << 16);
            float xf = __builtin_bit_cast(float, xs32);
            f32x2 s; s[0] = xf; s[1] = xf;
#pragma unroll
            for (int ks2 = 0; ks2 < 2; ++ks2) {
                u32x4 o;
#pragma unroll
                for (int q = 0; q < 4; ++q)
                    o[q] = scale_pack(xb[nf][ks2 * 4 + q], s);
                bw[ks2][nf] = __builtin_bit_cast(bf16x8, o);
            }
        }
#pragma unroll
        for (int ks2 = 0; ks2 < 2; ++ks2) {
            __builtin_amdgcn_s_setprio(1);
#pragma unroll
            for (int mf = 0; mf < 4; ++mf)
#pragma unroll
                for (int nf = 0; nf < 4; ++nf)
                    acc[mf][nf] = __builtin_amdgcn_mfma_f32_16x16x32_bf16(
                        af[ks2][mf], bw[ks2][nf], acc[mf][nf], 0, 0, 0);
            __builtin_amdgcn_s_setprio(0);
        }
    };

    auto CHUNK = [&](int c, const u32x4 (&cur)[4], u32x4 (&nxt)[4]) {
        int cn = c + 1; if (cn > NC - 1) cn = NC - 1;
#pragma unroll
        for (int nf = 0; nf < 4; ++nf) nxt[nf] = *(const u32x4*)(xrow[nf] + cn * 8);
#pragma unroll
        for (int gi = 0; gi < 8; ++gi)
            PROC_G(c * 8 + gi, cur, gi >> 1, gi & 1);
        __syncthreads();  // keep 4 waves phase-close -> L1 reuse of K rows
    };

#pragma unroll 1
    for (int c = 0; c < NC; c += 2) {
        CHUNK(c, xcA, xcB);
        CHUNK(c + 1, xcB, xcA);
    }

    // ---- epilogue: bias+relu, fm [n][128] coalesced uint2 store, pooled d-sum -> out ----
#pragma unroll
    for (int mf = 0; mf < 4; ++mf) {
        const int kk = wm * 64 + mf * 16 + g4 * 4;
        const float4 bs = *(const float4*)(bias + kk);
        float pool[2][4] = {{0.f, 0.f, 0.f, 0.f}, {0.f, 0.f, 0.f, 0.f}};
#pragma unroll
        for (int nf = 0; nf < 4; ++nf) {
            const size_t n_g = n0 + wn * 64 + nf * 16 + col;
            float v[4];
#pragma unroll
            for (int r = 0; r < 4; ++r) {
                float vv = acc[mf][nf][r] + ((r == 0) ? bs.x : (r == 1) ? bs.y : (r == 2) ? bs.z : bs.w);
                vv = fmaxf(vv, 0.f);
                v[r] = vv;
                pool[nf >> 1][r] += vv;
            }
            if (STORE_FM) {
                uint2 ww;
                ww.x = (u32)f2b_rne(v[0]) | ((u32)f2b_rne(v[1]) << 16);
                ww.y = (u32)f2b_rne(v[2]) | ((u32)f2b_rne(v[3]) << 16);
                *(uint2*)(fm_out + n_g * 128 + kk) = ww;
            }
        }
#pragma unroll
        for (int bi = 0; bi < 2; ++bi) {
#pragma unroll
            for (int r = 0; r < 4; ++r) {
                float s = pool[bi][r];
                s += __shfl_xor(s, 1, 16);
                s += __shfl_xor(s, 2, 16);
                s += __shfl_xor(s, 4, 16);
                s += __shfl_xor(s, 8, 16);
                pool[bi][r] = s;
            }
            if (col == 0) {
                const long b = (long)wg * 4 + wn * 2 + bi;
                float4 o;
                o.x = pool[bi][0]; o.y = pool[bi][1]; o.z = pool[bi][2]; o.w = pool[bi][3];
                *(float4*)(out + b * 384 + layer_off + kk) = o;
            }
        }
    }
}

extern "C" void kernel_launch(void* const* d_in, const int* in_sizes, int n_in,
                              void* d_out, int out_size, void* d_ws, size_t ws_size,
                              hipStream_t stream) {
    const float* x  = (const float*)d_in[0];
    const float* k0 = (const float*)d_in[1];
    const float* k1 = (const float*)d_in[2];
    const float* k2 = (const float*)d_in[3];
    const float* bb0 = (const float*)d_in[4];
    const float* bb1 = (const float*)d_in[5];
    const float* bb2 = (const float*)d_in[6];
    float* out = (float*)d_out;
    char* ws = (char*)d_ws;

    // workspace layout; total = 172,966,912 B
    ushort_t* x0bf = (ushort_t*)(ws);                 // 262144*64*2  = 33,554,432
    ushort_t* Kp0  = (ushort_t*)(ws + 33554432);      // 64*128*64*2  =  1,048,576
    ushort_t* Kp1  = (ushort_t*)(ws + 34603008);      // 128*128*64*2 =  2,097,152
    ushort_t* Kp2  = (ushort_t*)(ws + 36700160);      // 128*128*64*2 =  2,097,152
    ushort_t* fm0  = (ushort_t*)(ws + 38797312);      // 262144*128*2 = 67,108,864
    ushort_t* fm1  = (ushort_t*)(ws + 105906176);     // 262144*128*2 = 67,108,864

    cin_prep_x0bf<<<8192, 256, 0, stream>>>(x, x0bf);
    cin_prep_k3<<<64, 256, 0, stream>>>(k0, Kp0, 64);
    cin_prep_k3<<<128, 256, 0, stream>>>(k1, Kp1, 128);
    cin_prep_k3<<<128, 256, 0, stream>>>(k2, Kp2, 128);

    // layer 0: xi == x0 in [n][64] layout == x0bf itself
    cin_layer7<64, true><<<2048, 256, 0, stream>>>(x0bf, x0bf, Kp0, bb0, fm0, out, 0);
    cin_layer7<128, true><<<2048, 256, 0, stream>>>(x0bf, fm0, Kp1, bb1, fm1, out, 128);
    cin_layer7<128, false><<<2048, 256, 0, stream>>>(x0bf, fm1, Kp2, bb2, (ushort_t*)nullptr, out, 256);
}

// Round 10
// 1277.167 us; speedup vs baseline: 1.9163x; 1.9163x over previous
//
#include <hip/hip_runtime.h>

typedef unsigned short ushort_t;
typedef unsigned int u32;
typedef __attribute__((ext_vector_type(8))) short bf16x8;
typedef __attribute__((ext_vector_type(4))) float f32x4;
typedef __attribute__((ext_vector_type(2))) float f32x2;
typedef __attribute__((ext_vector_type(4))) u32 u32x4;

#define NTOT 262144  // B*D columns

__device__ __forceinline__ ushort_t f2b_rne(float f) {
    u32 u = __builtin_bit_cast(u32, f);
    u32 r = u + 0x7FFFu + ((u >> 16) & 1u);
    return (ushort_t)(r >> 16);
}
// (even,odd) f32 pair * (s,s) -> packed bf16 dword (RNE): v_pk_mul_f32 + v_cvt_pk_bf16_f32
__device__ __forceinline__ u32 scale_pack(f32x2 xp, f32x2 s) {
    f32x2 d;
    asm("v_pk_mul_f32 %0, %1, %2" : "=v"(d) : "v"(xp), "v"(s));
    u32 r;
    asm("v_cvt_pk_bf16_f32 %0, %1, %2" : "=v"(r) : "v"(d[0]), "v"(d[1]));
    return r;
}
__device__ __forceinline__ void gl_lds16(const ushort_t* g, ushort_t* l) {
    __builtin_amdgcn_global_load_lds(
        (const __attribute__((address_space(1))) u32*)g,
        (__attribute__((address_space(3))) u32*)l, 16, 0, 0);
}

// ---- prep: x (B,64,32) f32 -> x0bf bf16 [n=(b*32+d)][64 h] (RNE) ----
__global__ void cin_prep_x0bf(const float* __restrict__ x, ushort_t* __restrict__ x0bf) {
    __shared__ float xs[64 * 33];
    const int b = blockIdx.x, t = threadIdx.x;
    const float4* src = (const float4*)(x + (size_t)b * 2048);
#pragma unroll
    for (int i = 0; i < 2; ++i) {
        float4 f = src[t + 256 * i];
        int e = (t + 256 * i) * 4;
        int h = e >> 5, d = e & 31;
        xs[h * 33 + d]     = f.x;
        xs[h * 33 + d + 1] = f.y;
        xs[h * 33 + d + 2] = f.z;
        xs[h * 33 + d + 3] = f.w;
    }
    __syncthreads();
    const int d = t >> 3, j8 = t & 7;
    u32 w[4];
#pragma unroll
    for (int q = 0; q < 4; ++q) {
        int h0 = j8 * 8 + 2 * q;
        w[q] = (u32)f2b_rne(xs[h0 * 33 + d]) | ((u32)f2b_rne(xs[(h0 + 1) * 33 + d]) << 16);
    }
    uint4 o; o.x = w[0]; o.y = w[1]; o.z = w[2]; o.w = w[3];
    *(uint4*)(x0bf + ((size_t)b * 32 + d) * 64 + j8 * 8) = o;
}

// ---- prep: K (128,G,64) f32 -> Kp bf16 [g][k][64] with 16B-chunk XOR swizzle ----
__global__ void cin_prep_k2(const float* __restrict__ K, ushort_t* __restrict__ Kp, int G) {
    const int g = blockIdx.x, t = threadIdx.x;
    const int k = t >> 1, j0 = (t & 1) * 16;
    const float* s = K + ((size_t)k * G + g) * 64 + j0 * 2;
    u32* dst = (u32*)(Kp + (size_t)g * 8192 + k * 64);
    const int swc = k & 7;
#pragma unroll
    for (int c = 0; c < 4; ++c) {
        u32 w[4];
#pragma unroll
        for (int q = 0; q < 4; ++q) {
            int e = (c * 4 + q) * 2;
            w[q] = (u32)f2b_rne(s[e]) | ((u32)f2b_rne(s[e + 1]) << 16);
        }
        uint4 o; o.x = w[0]; o.y = w[1]; o.z = w[2]; o.w = w[3];
        *(uint4*)(dst + (((j0 >> 2) + c) ^ swc) * 4) = o;
    }
}

// ---- layer: fm[n,k] = relu( sum_g sum_h K[k,g,h]*xi[n,g]*x0[n,h] + bias[k] )
// 2 g's per iteration, 32 KB K-pair double-buffered via gload_lds (64 KB LDS),
// one vmcnt+barrier per pair. NO setprio / NO mid-body sched fences: program
// order interleaves af1 ds_reads under the MFMA0 burst so LDS/VALU/MFMA pipes
// overlap instead of serializing. xi in register chunks; B built in-register.
template <int G, bool STORE_FM>
__launch_bounds__(256, 2)
__global__ void cin_layer8(const ushort_t* __restrict__ x0bf,   // [NTOT][64]
                           const ushort_t* __restrict__ xi_src, // [NTOT][G] rows
                           const ushort_t* __restrict__ Kp,     // [G][128][64] swizzled
                           const float* __restrict__ bias,      // [128]
                           ushort_t* __restrict__ fm_out,       // [NTOT][128]
                           float* __restrict__ out,             // [B][384]
                           int layer_off) {
    constexpr int NIT = G / 2;    // pair-iterations
    constexpr int NBODY = G / 8;  // xi chunks (4 pair-iters each)
    __shared__ ushort_t k_lds[2][16384];  // 2 x 32 KB pair buffers

    const int t = threadIdx.x;
    const int wg = blockIdx.x;
    const int lane = t & 63;
    const int wave = t >> 6;
    const int wm = wave >> 1, wn = wave & 1;
    const int col = lane & 15, g4 = lane >> 4;
    const int swz = (col & 7) << 3;
    const size_t n0 = (size_t)wg * 128;

    auto issuePair = [&](int p, int buf) {  // stage g-pair p (32 KB)
        const ushort_t* src = Kp + (size_t)p * 16384 + (size_t)t * 8;
        ushort_t* dst = &k_lds[buf][0] + t * 8;
#pragma unroll
        for (int i = 0; i < 8; ++i) gl_lds16(src + i * 2048, dst + i * 2048);
    };

    // per-thread xi row pointers (one per nf)
    const ushort_t* xrow[4];
#pragma unroll
    for (int nf = 0; nf < 4; ++nf)
        xrow[nf] = xi_src + (n0 + wn * 64 + nf * 16 + col) * G;

    // ---- x0 base -> unpacked (even,odd) f32 pairs: 64 VGPRs ----
    f32x2 xb[4][8];
#pragma unroll
    for (int nf = 0; nf < 4; ++nf) {
        const size_t n_g = n0 + wn * 64 + nf * 16 + col;
#pragma unroll
        for (int ks2 = 0; ks2 < 2; ++ks2) {
            u32x4 v = *(const u32x4*)(x0bf + n_g * 64 + ks2 * 32 + g4 * 8);
#pragma unroll
            for (int q = 0; q < 4; ++q) {
                f32x2 p;
                p[0] = __builtin_bit_cast(float, v[q] << 16);
                p[1] = __builtin_bit_cast(float, v[q] & 0xFFFF0000u);
                xb[nf][ks2 * 4 + q] = p;
            }
        }
    }

    u32x4 xcA[4], xcB[4];
#pragma unroll
    for (int nf = 0; nf < 4; ++nf) xcA[nf] = *(const u32x4*)(xrow[nf]);  // chunk 0

    issuePair(0, 0);

    f32x4 acc[4][4];
#pragma unroll
    for (int a = 0; a < 4; ++a)
#pragma unroll
        for (int b = 0; b < 4; ++b) acc[a][b] = (f32x4){0.f, 0.f, 0.f, 0.f};

    asm volatile("s_waitcnt vmcnt(0)" ::: "memory");
    __builtin_amdgcn_s_barrier();
    __builtin_amdgcn_sched_barrier(0);

    // one iteration = one g-pair; ordered so af1 reads slot under the MFMA0 burst
    auto ITER = [&](int it, int bufr /*ct*/, const u32x4 (&cur)[4], int j /*ct*/) {
        int pn = it + 1; if (pn > NIT - 1) pn = NIT - 1;
        issuePair(pn, bufr ^ 1);
        const ushort_t* kbuf = &k_lds[bufr][0];
        // af0: A-fragments of first g
        bf16x8 af0[2][4];
#pragma unroll
        for (int ks2 = 0; ks2 < 2; ++ks2)
#pragma unroll
            for (int mf = 0; mf < 4; ++mf)
                af0[ks2][mf] = *(const bf16x8*)(kbuf + (wm * 64 + mf * 16 + col) * 64 +
                                                ((ks2 * 32 + g4 * 8) ^ swz));
        // B fragments for BOTH g's of the pair (independent VALU)
        bf16x8 bw0[2][4], bw1[2][4];
#pragma unroll
        for (int nf = 0; nf < 4; ++nf) {
            u32 xw = cur[nf][j];
            float xf0 = __builtin_bit_cast(float, xw << 16);
            float xf1 = __builtin_bit_cast(float, xw & 0xFFFF0000u);
            f32x2 s0; s0[0] = xf0; s0[1] = xf0;
            f32x2 s1; s1[0] = xf1; s1[1] = xf1;
#pragma unroll
            for (int ks2 = 0; ks2 < 2; ++ks2) {
                u32x4 o0, o1;
#pragma unroll
                for (int q = 0; q < 4; ++q) {
                    o0[q] = scale_pack(xb[nf][ks2 * 4 + q], s0);
                    o1[q] = scale_pack(xb[nf][ks2 * 4 + q], s1);
                }
                bw0[ks2][nf] = __builtin_bit_cast(bf16x8, o0);
                bw1[ks2][nf] = __builtin_bit_cast(bf16x8, o1);
            }
        }
        // MFMA burst for g0
#pragma unroll
        for (int ks2 = 0; ks2 < 2; ++ks2)
#pragma unroll
            for (int mf = 0; mf < 4; ++mf)
#pragma unroll
                for (int nf = 0; nf < 4; ++nf)
                    acc[mf][nf] = __builtin_amdgcn_mfma_f32_16x16x32_bf16(
                        af0[ks2][mf], bw0[ks2][nf], acc[mf][nf], 0, 0, 0);
        // af1 reads (scheduler can issue these under the MFMA0 burst)
        bf16x8 af1[2][4];
#pragma unroll
        for (int ks2 = 0; ks2 < 2; ++ks2)
#pragma unroll
            for (int mf = 0; mf < 4; ++mf)
                af1[ks2][mf] = *(const bf16x8*)(kbuf + 8192 +
                                                (wm * 64 + mf * 16 + col) * 64 +
                                                ((ks2 * 32 + g4 * 8) ^ swz));
        // MFMA burst for g1
#pragma unroll
        for (int ks2 = 0; ks2 < 2; ++ks2)
#pragma unroll
            for (int mf = 0; mf < 4; ++mf)
#pragma unroll
                for (int nf = 0; nf < 4; ++nf)
                    acc[mf][nf] = __builtin_amdgcn_mfma_f32_16x16x32_bf16(
                        af1[ks2][mf], bw1[ks2][nf], acc[mf][nf], 0, 0, 0);
        asm volatile("s_waitcnt vmcnt(0)" ::: "memory");  // next pair landed (lead ~1 iter)
        __builtin_amdgcn_s_barrier();
        __builtin_amdgcn_sched_barrier(0);
    };

#pragma unroll 1
    for (int bp = 0; bp < NBODY / 2; ++bp) {
        {   // body 2bp: consumes xcA, prefetches chunk 2bp+1 into xcB
            int cn = 2 * bp + 1; if (cn > NBODY - 1) cn = NBODY - 1;
#pragma unroll
            for (int nf = 0; nf < 4; ++nf) xcB[nf] = *(const u32x4*)(xrow[nf] + cn * 8);
            const int itB = bp * 8;
            ITER(itB + 0, 0, xcA, 0);
            ITER(itB + 1, 1, xcA, 1);
            ITER(itB + 2, 0, xcA, 2);
            ITER(itB + 3, 1, xcA, 3);
        }
        {   // body 2bp+1: consumes xcB, prefetches chunk 2bp+2 into xcA
            int cn = 2 * bp + 2; if (cn > NBODY - 1) cn = NBODY - 1;
#pragma unroll
            for (int nf = 0; nf < 4; ++nf) xcA[nf] = *(const u32x4*)(xrow[nf] + cn * 8);
            const int itB = bp * 8 + 4;
            ITER(itB + 0, 0, xcB, 0);
            ITER(itB + 1, 1, xcB, 1);
            ITER(itB + 2, 0, xcB, 2);
            ITER(itB + 3, 1, xcB, 3);
        }
    }

    // ---- epilogue: bias+relu, fm [n][128] coalesced uint2 store, pooled d-sum -> out ----
#pragma unroll
    for (int mf = 0; mf < 4; ++mf) {
        const int kk = wm * 64 + mf * 16 + g4 * 4;
        const float4 bs = *(const float4*)(bias + kk);
        float pool[2][4] = {{0.f, 0.f, 0.f, 0.f}, {0.f, 0.f, 0.f, 0.f}};
#pragma unroll
        for (int nf = 0; nf < 4; ++nf) {
            const size_t n_g = n0 + wn * 64 + nf * 16 + col;
            float v[4];
#pragma unroll
            for (int r = 0; r < 4; ++r) {
                float vv = acc[mf][nf][r] + ((r == 0) ? bs.x : (r == 1) ? bs.y : (r == 2) ? bs.z : bs.w);
                vv = fmaxf(vv, 0.f);
                v[r] = vv;
                pool[nf >> 1][r] += vv;
            }
            if (STORE_FM) {
                uint2 ww;
                ww.x = (u32)f2b_rne(v[0]) | ((u32)f2b_rne(v[1]) << 16);
                ww.y = (u32)f2b_rne(v[2]) | ((u32)f2b_rne(v[3]) << 16);
                *(uint2*)(fm_out + n_g * 128 + kk) = ww;
            }
        }
#pragma unroll
        for (int bi = 0; bi < 2; ++bi) {
#pragma unroll
            for (int r = 0; r < 4; ++r) {
                float s = pool[bi][r];
                s += __shfl_xor(s, 1, 16);
                s += __shfl_xor(s, 2, 16);
                s += __shfl_xor(s, 4, 16);
                s += __shfl_xor(s, 8, 16);
                pool[bi][r] = s;
            }
            if (col == 0) {
                const long b = (long)wg * 4 + wn * 2 + bi;
                float4 o;
                o.x = pool[bi][0]; o.y = pool[bi][1]; o.z = pool[bi][2]; o.w = pool[bi][3];
                *(float4*)(out + b * 384 + layer_off + kk) = o;
            }
        }
    }
}

extern "C" void kernel_launch(void* const* d_in, const int* in_sizes, int n_in,
                              void* d_out, int out_size, void* d_ws, size_t ws_size,
                              hipStream_t stream) {
    const float* x  = (const float*)d_in[0];
    const float* k0 = (const float*)d_in[1];
    const float* k1 = (const float*)d_in[2];
    const float* k2 = (const float*)d_in[3];
    const float* bb0 = (const float*)d_in[4];
    const float* bb1 = (const float*)d_in[5];
    const float* bb2 = (const float*)d_in[6];
    float* out = (float*)d_out;
    char* ws = (char*)d_ws;

    // workspace layout; total = 172,966,912 B
    ushort_t* x0bf = (ushort_t*)(ws);                 // 262144*64*2  = 33,554,432
    ushort_t* Kp0  = (ushort_t*)(ws + 33554432);      // 64*128*64*2  =  1,048,576
    ushort_t* Kp1  = (ushort_t*)(ws + 34603008);      // 128*128*64*2 =  2,097,152
    ushort_t* Kp2  = (ushort_t*)(ws + 36700160);      // 128*128*64*2 =  2,097,152
    ushort_t* fm0  = (ushort_t*)(ws + 38797312);      // 262144*128*2 = 67,108,864
    ushort_t* fm1  = (ushort_t*)(ws + 105906176);     // 262144*128*2 = 67,108,864

    cin_prep_x0bf<<<8192, 256, 0, stream>>>(x, x0bf);
    cin_prep_k2<<<64, 256, 0, stream>>>(k0, Kp0, 64);
    cin_prep_k2<<<128, 256, 0, stream>>>(k1, Kp1, 128);
    cin_prep_k2<<<128, 256, 0, stream>>>(k2, Kp2, 128);

    // layer 0: xi == x0 in [n][64] layout == x0bf itself
    cin_layer8<64, true><<<2048, 256, 0, stream>>>(x0bf, x0bf, Kp0, bb0, fm0, out, 0);
    cin_layer8<128, true><<<2048, 256, 0, stream>>>(x0bf, fm0, Kp1, bb1, fm1, out, 128);
    cin_layer8<128, false><<<2048, 256, 0, stream>>>(x0bf, fm1, Kp2, bb2, (ushort_t*)nullptr, out, 256);
}